// Round 9
// baseline (75.154 us; speedup 1.0000x reference)
//
#include <hip/hip_runtime.h>

typedef __attribute__((ext_vector_type(8))) short short8;
typedef __attribute__((ext_vector_type(4))) float f32x4;
typedef __attribute__((ext_vector_type(4))) int   i32x4;

#define IN_F   4096
#define OUT_F  16384
#define NG     32
#define BKI    256          // ints per chunk per row = 1 KB granule
#define NIT    32           // 2 col-groups x 16 chunks

// f32 -> bf16 round-to-nearest-even
static __device__ __forceinline__ short f2bf(float f) {
    union { float f; unsigned u; } c; c.f = f;
    unsigned u = c.u;
    u += 0x7FFF + ((u >> 16) & 1);
    return (short)(u >> 16);
}

// int8-range -> bf16 (exact for |v| <= 127)
static __device__ __forceinline__ short i2bf(int v) {
    union { float f; unsigned u; } c; c.f = (float)v;
    return (short)(c.u >> 16);
}

// Pre-pass: x[32][4096] f32 -> xT bf16 in MFMA-A-fragment order.
// xT layout: [t][h][ln][8] bf16, t = k/32, h = m-half, ln = l15*4 + l4.
__global__ __launch_bounds__(256)
void xconv_kernel(const float* __restrict__ x, unsigned short* __restrict__ xT) {
    const int g   = blockIdx.x * 256 + threadIdx.x;   // 16384 threads
    const int t   = g >> 7;
    const int rem = g & 127;
    const int h   = rem >> 6;
    const int ln  = rem & 63;
    const int l15 = ln >> 2;
    const int l4  = ln & 3;
    const float* src = x + (size_t)(16 * h + l15) * IN_F + t * 32 + l4 * 8;
    f32x4 a = *(const f32x4*)src;
    f32x4 b = *(const f32x4*)(src + 4);
    short8 o;
#pragma unroll
    for (int j = 0; j < 4; ++j) { o[j] = f2bf(a[j]); o[j + 4] = f2bf(b[j]); }
    *(short8*)(xT + (size_t)g * 8) = o;
}

// Main: grid 256 = exactly 1 block/CU. 512 thr = 8 waves; block owns 64
// out-cols as TWO sequential 32-col groups (16 chunks each, 32 intervals).
// Per interval: stage 32 rows x 1 KB contiguous (1 KB DRAM granule/stream),
// 3-slot rotation, depth-2 counted vmcnt(8), never drained mid-kernel.
// wk = K-half within chunk, (wm,wn) = 16x16 tile. Swizzle per rule #21.
__global__ __launch_bounds__(512, 2)
void qlin_kernel(const unsigned short* __restrict__ xT,
                 const int*   __restrict__ qw,
                 const float* __restrict__ scales,
                 const float* __restrict__ bias,
                 float*       __restrict__ out)
{
    __shared__ int   lqw[3][32][BKI];   // 96 KB
    __shared__ float red[8][64][4];     // 8 KB (separate: no alias w/ live slots)

    const int tid  = threadIdx.x;
    const int wv   = tid >> 6;
    const int lane = tid & 63;
    const int l15  = lane & 15;
    const int l4   = lane >> 4;
    const int wk   = wv >> 2;         // K-half within chunk
    const int wm   = (wv >> 1) & 1;   // m-half
    const int wn   = wv & 1;          // n-half
    const int colbase = blockIdx.x * 64;
    const int rowB = 16 * wn + l15;   // LDS row = out-col within group
    const int swzB = (rowB & 7) << 4;

    // scales/bias preload (issued first -> oldest -> retired by prologue wait)
    float sc_arr[NIT];
    {
        const float* s0 = scales + (size_t)(colbase + rowB) * NG + wk;
        const float* s1 = scales + (size_t)(colbase + 32 + rowB) * NG + wk;
#pragma unroll
        for (int c = 0; c < 16; ++c) {
            sc_arr[c]      = s0[2 * c];
            sc_arr[16 + c] = s1[2 * c];
        }
    }
    const float bv0 = bias[colbase + rowB];
    const float bv1 = bias[colbase + 32 + rowB];

    // stage interval j into slot sl: 4 instrs/wave, each one row's FULL 1 KB
    // contiguous; source pre-swizzled by ((row&7)<<4), LDS dest linear.
    auto STAGE = [&](int j, int sl) {
        const int G = j >> 4, c = j & 15;
        const int col0 = colbase + G * 32;
#pragma unroll
        for (int i = 0; i < 4; ++i) {
            const int row = 4 * wv + i;
            const int byt = (lane * 16) ^ ((row & 7) << 4);
            const char* src = (const char*)(qw + (size_t)(col0 + row) * IN_F + c * BKI) + byt;
            __builtin_amdgcn_global_load_lds(
                (const __attribute__((address_space(1))) unsigned int*)src,
                (__attribute__((address_space(3))) unsigned int*)&lqw[sl][row][0],
                16, 0, 0);
        }
    };

    // x fragments: wave's 4 k-tiles per interval (4 KB contiguous), parity-2 park
    const unsigned short* xgrp = xT + (size_t)(l15 * 4 + l4) * 8 + (size_t)wm * 512;
    short8 xa[2][4];
    auto XLOAD = [&](int j, int par) {
        const int t = (j & 15) * 8 + wk * 4;
#pragma unroll
        for (int s = 0; s < 4; ++s)
            xa[par][s] = *(const short8*)(xgrp + (size_t)(t + s) * 1024);
    };

    f32x4 acc = {0.f, 0.f, 0.f, 0.f};

    auto COMPUTE = [&](int j, int sl, int par, float sc) {
        const char* lrow = (const char*)&lqw[sl][rowB][0];
        f32x4 ag = {0.f, 0.f, 0.f, 0.f};
#pragma unroll
        for (int s = 0; s < 4; ++s) {
            const int off = (wk * 512 + s * 128 + l4 * 32) ^ swzB;
            i32x4 q0 = *(const i32x4*)(lrow + off);
            i32x4 q1 = *(const i32x4*)(lrow + (off ^ 16));
            short8 bfr;
#pragma unroll
            for (int u = 0; u < 4; ++u) { bfr[u] = i2bf(q0[u]); bfr[u + 4] = i2bf(q1[u]); }
            ag = __builtin_amdgcn_mfma_f32_16x16x32_bf16(xa[par][s], bfr, ag, 0, 0, 0);
        }
#pragma unroll
        for (int r = 0; r < 4; ++r) acc[r] += sc * ag[r];
    };

    // reduce wk-halves + store group G; raw lgkm-only barrier (no vmcnt drain)
    auto REDSTORE = [&](int G, float bv) {
        *(f32x4*)&red[wv][lane][0] = acc;
        asm volatile("s_waitcnt lgkmcnt(0)" ::: "memory");
        __builtin_amdgcn_s_barrier();
        if (wv < 4) {
            const int col = colbase + G * 32 + rowB;
            f32x4 lo = *(const f32x4*)&red[wv][lane][0];
            f32x4 hi = *(const f32x4*)&red[wv + 4][lane][0];
#pragma unroll
            for (int r = 0; r < 4; ++r)
                out[(size_t)(16 * wm + l4 * 4 + r) * OUT_F + col] = lo[r] + hi[r] + bv;
        }
        acc = (f32x4){0.f, 0.f, 0.f, 0.f};
    };

    // --- prologue: s(0),x(0),s(1),x(1); vmcnt(8) keeps {s(1),x(1)} in flight ---
    STAGE(0, 0);
    asm volatile("" ::: "memory");
    XLOAD(0, 0);
    asm volatile("" ::: "memory");
    STAGE(1, 1);
    asm volatile("" ::: "memory");
    XLOAD(1, 1);
    asm volatile("s_waitcnt vmcnt(8)" ::: "memory");
    __builtin_amdgcn_s_barrier();
    __builtin_amdgcn_sched_barrier(0);

    // --- steady: compute(j) || {x(j+2), stage(j+2)}; vmcnt(8), never 0 ---
#pragma unroll
    for (int j = 0; j < 30; ++j) {
        COMPUTE(j, j % 3, j & 1, sc_arr[j]);
        XLOAD(j + 2, j & 1);
        asm volatile("" ::: "memory");
        STAGE(j + 2, (j + 2) % 3);
        asm volatile("s_waitcnt vmcnt(8)" ::: "memory");
        __builtin_amdgcn_s_barrier();
        __builtin_amdgcn_sched_barrier(0);
        if (j == 15) REDSTORE(0, bv0);   // group-0 epilogue; pipeline stays live
    }

    // --- tail ---
    COMPUTE(30, 0, 0, sc_arr[30]);
    asm volatile("s_waitcnt vmcnt(0)" ::: "memory");
    __builtin_amdgcn_s_barrier();
    __builtin_amdgcn_sched_barrier(0);
    COMPUTE(31, 1, 1, sc_arr[31]);
    REDSTORE(1, bv1);
}

extern "C" void kernel_launch(void* const* d_in, const int* in_sizes, int n_in,
                              void* d_out, int out_size, void* d_ws, size_t ws_size,
                              hipStream_t stream) {
    const float* x      = (const float*)d_in[0];
    const int*   qw     = (const int*)d_in[1];
    const float* scales = (const float*)d_in[2];
    const float* bias   = (const float*)d_in[3];
    float*       out    = (float*)d_out;
    unsigned short* xT  = (unsigned short*)d_ws;   // 256 KB fragment-ordered x

    hipLaunchKernelGGL(xconv_kernel, dim3(64), dim3(256), 0, stream, x, xT);
    hipLaunchKernelGGL(qlin_kernel, dim3(OUT_F / 64), dim3(512), 0, stream,
                       xT, qw, scales, bias, out);
}

// Round 10
// 58.389 us; speedup vs baseline: 1.2871x; 1.2871x over previous
//
#include <hip/hip_runtime.h>

typedef __attribute__((ext_vector_type(8))) short short8;
typedef __attribute__((ext_vector_type(4))) float f32x4;
typedef __attribute__((ext_vector_type(4))) int   i32x4;

#define IN_F   4096
#define OUT_F  16384
#define NG     32
#define BK     64           // ints per chunk
#define NCH    32           // chunks per K-half (2048/64)

// f32 -> bf16 round-to-nearest-even
static __device__ __forceinline__ short f2bf(float f) {
    union { float f; unsigned u; } c; c.f = f;
    unsigned u = c.u;
    u += 0x7FFF + ((u >> 16) & 1);
    return (short)(u >> 16);
}

// int8-range -> bf16 (exact for |v| <= 127)
static __device__ __forceinline__ short i2bf(int v) {
    union { float f; unsigned u; } c; c.f = (float)v;
    return (short)(c.u >> 16);
}

// Pre-pass: x[32][4096] f32 -> xT bf16 in MFMA-A-fragment order.
// xT layout: [t][h][ln][8] bf16, t = k/32, h = m-half, ln = l15*4 + l4.
__global__ __launch_bounds__(256)
void xconv_kernel(const float* __restrict__ x, unsigned short* __restrict__ xT) {
    const int g   = blockIdx.x * 256 + threadIdx.x;   // 16384 threads
    const int t   = g >> 7;
    const int rem = g & 127;
    const int h   = rem >> 6;
    const int ln  = rem & 63;
    const int l15 = ln >> 2;
    const int l4  = ln & 3;
    const float* src = x + (size_t)(16 * h + l15) * IN_F + t * 32 + l4 * 8;
    f32x4 a = *(const f32x4*)src;
    f32x4 b = *(const f32x4*)(src + 4);
    short8 o;
#pragma unroll
    for (int j = 0; j < 4; ++j) { o[j] = f2bf(a[j]); o[j + 4] = f2bf(b[j]); }
    *(short8*)(xT + (size_t)g * 8) = o;
}

// Main (R6 + depth-3 + NT staging): 512 thr = 8 waves, 32 out-cols/block,
// grid 512 -> 2 blocks/CU. wk = K-half, (wm,wn) = 16x16 tile.
// 4 LDS slots, stage distance 3, steady-state s_waitcnt vmcnt(6) (never 0).
__global__ __launch_bounds__(512, 4)
void qlin_kernel(const unsigned short* __restrict__ xT,
                 const int*   __restrict__ qw,
                 const float* __restrict__ scales,
                 const float* __restrict__ bias,
                 float*       __restrict__ out)
{
    __shared__ int lqw[2][4][32][BK];   // 64 KB; aliased as `red` in epilogue

    const int tid  = threadIdx.x;
    const int wv   = tid >> 6;
    const int lane = tid & 63;
    const int l15  = lane & 15;
    const int l4   = lane >> 4;
    const int wk   = wv >> 2;         // K-half
    const int wm   = (wv >> 1) & 1;   // m-half
    const int wn   = wv & 1;          // n-half
    const int widx = wv & 3;
    const int col0 = blockIdx.x * 32;

    const int rowB = 16 * wn + l15;
    const int swzB = (rowB & 7) << 4;

    // --- stage chunk c of this wave's K-half into slot sl ---
    // 2 instrs/wave, each 1 KB = 4 rows x 256 B, LDS linear; global source
    // pre-swizzled by ((row&7)<<4) (read applies same XOR; rule #21).
    // aux=2 = NT: qw is read-once; don't evict L2-resident xT.
    auto STAGE = [&](int c, int sl) {
        const size_t kbase = (size_t)wk * 2048 + (size_t)c * BK;
#pragma unroll
        for (int i = 0; i < 2; ++i) {
            const int p   = widx * 2 + i;            // 0..7
            const int row = 4 * p + (lane >> 4);
            const int byt = ((lane & 15) * 16) ^ ((row & 7) << 4);
            const char* src = (const char*)(qw + (size_t)(col0 + row) * IN_F + kbase) + byt;
            __builtin_amdgcn_global_load_lds(
                (const __attribute__((address_space(1))) unsigned int*)src,
                (__attribute__((address_space(3))) unsigned int*)&lqw[wk][sl][4 * p][0],
                16, 0, 2);
        }
    };

    // --- x fragments: register park, distance 2, parity 2 ---
    const unsigned short* xgrp = xT + (size_t)(l15 * 4 + l4) * 8 + (size_t)wm * 512;
    short8 xa[2][2];                   // [parity][step]
    auto XLOAD = [&](int c, int par) {
        const int t = wk * 64 + c * 2;
        xa[par][0] = *(const short8*)(xgrp + (size_t)t * 1024);
        xa[par][1] = *(const short8*)(xgrp + (size_t)(t + 1) * 1024);
    };

    // --- scales: all 16 groups of this wave's K-half, preloaded ---
    const float* scr = scales + (size_t)(col0 + rowB) * NG + wk * 16;
    f32x4 sc4[4];
#pragma unroll
    for (int j = 0; j < 4; ++j) sc4[j] = *(const f32x4*)(scr + 4 * j);

    f32x4 acc = {0.f, 0.f, 0.f, 0.f};

    // --- compute chunk c from slot sl, x parity par (all indices static) ---
    auto COMPUTE = [&](int c, int sl, int par, float sc) {
        const char* lrow = (const char*)&lqw[wk][sl][rowB][0];
        f32x4 ag = {0.f, 0.f, 0.f, 0.f};
#pragma unroll
        for (int s = 0; s < 2; ++s) {
            const int byte0 = (s * 128 + l4 * 32) ^ swzB;
            i32x4 q0 = *(const i32x4*)(lrow + byte0);
            i32x4 q1 = *(const i32x4*)(lrow + (byte0 ^ 16));
            short8 bfr;
#pragma unroll
            for (int j = 0; j < 4; ++j) { bfr[j] = i2bf(q0[j]); bfr[j + 4] = i2bf(q1[j]); }
            ag = __builtin_amdgcn_mfma_f32_16x16x32_bf16(xa[par][s], bfr, ag, 0, 0, 0);
        }
#pragma unroll
        for (int r = 0; r < 4; ++r) acc[r] += sc * ag[r];
    };

    // --- prologue: st0, x0, x1, st1, st2; vmcnt(6) retires {st0, x0} ---
    STAGE(0, 0);
    asm volatile("" ::: "memory");
    XLOAD(0, 0);
    XLOAD(1, 1);
    asm volatile("" ::: "memory");
    STAGE(1, 1);
    STAGE(2, 2);
    asm volatile("s_waitcnt vmcnt(6)" ::: "memory");
    __builtin_amdgcn_s_barrier();
    __builtin_amdgcn_sched_barrier(0);

    // --- steady: compute(i) || {x(i+2), stage(i+3)}; vmcnt(6), never 0 ---
    // At each wait: in flight = {stage(i+2), x(i+2), stage(i+3)} = 6;
    // retires stage(i+1) + x(i+1) -> next interval's inputs ready.
#pragma unroll
    for (int i = 0; i <= 28; ++i) {
        COMPUTE(i, i & 3, i & 1, sc4[i >> 3][(i >> 1) & 3]);
        XLOAD(i + 2, i & 1);
        asm volatile("" ::: "memory");
        STAGE(i + 3, (i + 3) & 3);
        asm volatile("s_waitcnt vmcnt(6)" ::: "memory");
        __builtin_amdgcn_s_barrier();
        __builtin_amdgcn_sched_barrier(0);
    }
    // i=29: no stage left; keep {st31, x31} in flight
    COMPUTE(29, 1, 1, sc4[3][2]);
    XLOAD(31, 1);
    asm volatile("s_waitcnt vmcnt(4)" ::: "memory");
    __builtin_amdgcn_s_barrier();
    __builtin_amdgcn_sched_barrier(0);
    // i=30: drain
    COMPUTE(30, 2, 0, sc4[3][3]);
    asm volatile("s_waitcnt vmcnt(0)" ::: "memory");
    __builtin_amdgcn_s_barrier();
    __builtin_amdgcn_sched_barrier(0);
    COMPUTE(31, 3, 1, sc4[3][3]);

    // --- epilogue: cross-wk reduce through aliased LDS (slot 0, wk 0) ---
    __syncthreads();
    float* red = (float*)&lqw[0][0][0][0];    // [8][64][4] = 8 KB
    *(f32x4*)&red[(size_t)(wv * 64 + lane) * 4] = acc;
    __syncthreads();
    if (wv < 4) {
        const int col = col0 + rowB;
        const float bv = bias[col];
        f32x4 lo = *(const f32x4*)&red[(size_t)(wv * 64 + lane) * 4];
        f32x4 hi = *(const f32x4*)&red[(size_t)((wv + 4) * 64 + lane) * 4];
#pragma unroll
        for (int r = 0; r < 4; ++r)
            out[(size_t)(16 * wm + l4 * 4 + r) * OUT_F + col] = lo[r] + hi[r] + bv;
    }
}

extern "C" void kernel_launch(void* const* d_in, const int* in_sizes, int n_in,
                              void* d_out, int out_size, void* d_ws, size_t ws_size,
                              hipStream_t stream) {
    const float* x      = (const float*)d_in[0];
    const int*   qw     = (const int*)d_in[1];
    const float* scales = (const float*)d_in[2];
    const float* bias   = (const float*)d_in[3];
    float*       out    = (float*)d_out;
    unsigned short* xT  = (unsigned short*)d_ws;   // 256 KB fragment-ordered x

    hipLaunchKernelGGL(xconv_kernel, dim3(64), dim3(256), 0, stream, x, xT);
    hipLaunchKernelGGL(qlin_kernel, dim3(OUT_F / 32), dim3(512), 0, stream,
                       xT, qw, scales, bias, out);
}

// Round 11
// 53.053 us; speedup vs baseline: 1.4166x; 1.1006x over previous
//
#include <hip/hip_runtime.h>

typedef __attribute__((ext_vector_type(8))) short short8;
typedef __attribute__((ext_vector_type(4))) float f32x4;
typedef __attribute__((ext_vector_type(4))) int   i32x4;

#define IN_F   4096
#define OUT_F  16384
#define NG     32
#define BK     64           // ints per chunk
#define NCH    32           // chunks per K-half (2048/64)

// f32 -> bf16 round-to-nearest-even
static __device__ __forceinline__ short f2bf(float f) {
    union { float f; unsigned u; } c; c.f = f;
    unsigned u = c.u;
    u += 0x7FFF + ((u >> 16) & 1);
    return (short)(u >> 16);
}

// int8-range -> bf16 (exact for |v| <= 127)
static __device__ __forceinline__ short i2bf(int v) {
    union { float f; unsigned u; } c; c.f = (float)v;
    return (short)(c.u >> 16);
}

// Pre-pass: x[32][4096] f32 -> xT bf16 in MFMA-A-fragment order.
// xT layout: [t][h][ln][8] bf16, t = k/32, h = m-half, ln = l15*4 + l4.
__global__ __launch_bounds__(256)
void xconv_kernel(const float* __restrict__ x, unsigned short* __restrict__ xT) {
    const int g   = blockIdx.x * 256 + threadIdx.x;   // 16384 threads
    const int t   = g >> 7;
    const int rem = g & 127;
    const int h   = rem >> 6;
    const int ln  = rem & 63;
    const int l15 = ln >> 2;
    const int l4  = ln & 3;
    const float* src = x + (size_t)(16 * h + l15) * IN_F + t * 32 + l4 * 8;
    f32x4 a = *(const f32x4*)src;
    f32x4 b = *(const f32x4*)(src + 4);
    short8 o;
#pragma unroll
    for (int j = 0; j < 4; ++j) { o[j] = f2bf(a[j]); o[j + 4] = f2bf(b[j]); }
    *(short8*)(xT + (size_t)g * 8) = o;
}

// Main (R6 + depth-3, aux=0): 512 thr = 8 waves, 32 out-cols/block,
// grid 512 -> 2 blocks/CU. wk = K-half, (wm,wn) = 16x16 tile.
// 4 LDS slots, stage distance 3, steady-state s_waitcnt vmcnt(6) (never 0).
__global__ __launch_bounds__(512, 4)
void qlin_kernel(const unsigned short* __restrict__ xT,
                 const int*   __restrict__ qw,
                 const float* __restrict__ scales,
                 const float* __restrict__ bias,
                 float*       __restrict__ out)
{
    __shared__ int lqw[2][4][32][BK];   // 64 KB; aliased as `red` in epilogue

    const int tid  = threadIdx.x;
    const int wv   = tid >> 6;
    const int lane = tid & 63;
    const int l15  = lane & 15;
    const int l4   = lane >> 4;
    const int wk   = wv >> 2;         // K-half
    const int wm   = (wv >> 1) & 1;   // m-half
    const int wn   = wv & 1;          // n-half
    const int widx = wv & 3;
    const int col0 = blockIdx.x * 32;

    const int rowB = 16 * wn + l15;
    const int swzB = (rowB & 7) << 4;

    // --- stage chunk c of this wave's K-half into slot sl ---
    // 2 instrs/wave, each 1 KB = 4 rows x 256 B, LDS linear; global source
    // pre-swizzled by ((row&7)<<4) (read applies same XOR; rule #21). aux=0.
    auto STAGE = [&](int c, int sl) {
        const size_t kbase = (size_t)wk * 2048 + (size_t)c * BK;
#pragma unroll
        for (int i = 0; i < 2; ++i) {
            const int p   = widx * 2 + i;            // 0..7
            const int row = 4 * p + (lane >> 4);
            const int byt = ((lane & 15) * 16) ^ ((row & 7) << 4);
            const char* src = (const char*)(qw + (size_t)(col0 + row) * IN_F + kbase) + byt;
            __builtin_amdgcn_global_load_lds(
                (const __attribute__((address_space(1))) unsigned int*)src,
                (__attribute__((address_space(3))) unsigned int*)&lqw[wk][sl][4 * p][0],
                16, 0, 0);
        }
    };

    // --- x fragments: register park, distance 2, parity 2 ---
    const unsigned short* xgrp = xT + (size_t)(l15 * 4 + l4) * 8 + (size_t)wm * 512;
    short8 xa[2][2];                   // [parity][step]
    auto XLOAD = [&](int c, int par) {
        const int t = wk * 64 + c * 2;
        xa[par][0] = *(const short8*)(xgrp + (size_t)t * 1024);
        xa[par][1] = *(const short8*)(xgrp + (size_t)(t + 1) * 1024);
    };

    // --- scales: all 16 groups of this wave's K-half, preloaded ---
    const float* scr = scales + (size_t)(col0 + rowB) * NG + wk * 16;
    f32x4 sc4[4];
#pragma unroll
    for (int j = 0; j < 4; ++j) sc4[j] = *(const f32x4*)(scr + 4 * j);

    f32x4 acc = {0.f, 0.f, 0.f, 0.f};

    // --- compute chunk c from slot sl, x parity par (all indices static) ---
    auto COMPUTE = [&](int c, int sl, int par, float sc) {
        const char* lrow = (const char*)&lqw[wk][sl][rowB][0];
        f32x4 ag = {0.f, 0.f, 0.f, 0.f};
#pragma unroll
        for (int s = 0; s < 2; ++s) {
            const int byte0 = (s * 128 + l4 * 32) ^ swzB;
            i32x4 q0 = *(const i32x4*)(lrow + byte0);
            i32x4 q1 = *(const i32x4*)(lrow + (byte0 ^ 16));
            short8 bfr;
#pragma unroll
            for (int j = 0; j < 4; ++j) { bfr[j] = i2bf(q0[j]); bfr[j + 4] = i2bf(q1[j]); }
            ag = __builtin_amdgcn_mfma_f32_16x16x32_bf16(xa[par][s], bfr, ag, 0, 0, 0);
        }
#pragma unroll
        for (int r = 0; r < 4; ++r) acc[r] += sc * ag[r];
    };

    // --- prologue: st0, x0, x1, st1, st2; vmcnt(6) retires {st0, x0} ---
    STAGE(0, 0);
    asm volatile("" ::: "memory");
    XLOAD(0, 0);
    XLOAD(1, 1);
    asm volatile("" ::: "memory");
    STAGE(1, 1);
    STAGE(2, 2);
    asm volatile("s_waitcnt vmcnt(6)" ::: "memory");
    __builtin_amdgcn_s_barrier();
    __builtin_amdgcn_sched_barrier(0);

    // --- steady: compute(i) || {x(i+2), stage(i+3)}; vmcnt(6), never 0 ---
    // Induction: at iter-i wait, outstanding {st(i+2), x(i+2), st(i+3)} = 6;
    // retires st(i+1), x(i+1) -> next interval's inputs ready.
#pragma unroll
    for (int i = 0; i <= 28; ++i) {
        COMPUTE(i, i & 3, i & 1, sc4[i >> 3][(i >> 1) & 3]);
        XLOAD(i + 2, i & 1);
        asm volatile("" ::: "memory");
        STAGE(i + 3, (i + 3) & 3);
        asm volatile("s_waitcnt vmcnt(6)" ::: "memory");
        __builtin_amdgcn_s_barrier();
        __builtin_amdgcn_sched_barrier(0);
    }
    // i=29: no stage left; keep {st31, x31} in flight
    COMPUTE(29, 1, 1, sc4[3][2]);
    XLOAD(31, 1);
    asm volatile("s_waitcnt vmcnt(4)" ::: "memory");
    __builtin_amdgcn_s_barrier();
    __builtin_amdgcn_sched_barrier(0);
    // i=30: drain
    COMPUTE(30, 2, 0, sc4[3][3]);
    asm volatile("s_waitcnt vmcnt(0)" ::: "memory");
    __builtin_amdgcn_s_barrier();
    __builtin_amdgcn_sched_barrier(0);
    COMPUTE(31, 3, 1, sc4[3][3]);

    // --- epilogue: cross-wk reduce through aliased LDS (slot 0, wk 0) ---
    __syncthreads();
    float* red = (float*)&lqw[0][0][0][0];    // [8][64][4] = 8 KB
    *(f32x4*)&red[(size_t)(wv * 64 + lane) * 4] = acc;
    __syncthreads();
    if (wv < 4) {
        const int col = col0 + rowB;
        const float bv = bias[col];
        f32x4 lo = *(const f32x4*)&red[(size_t)(wv * 64 + lane) * 4];
        f32x4 hi = *(const f32x4*)&red[(size_t)((wv + 4) * 64 + lane) * 4];
#pragma unroll
        for (int r = 0; r < 4; ++r)
            out[(size_t)(16 * wm + l4 * 4 + r) * OUT_F + col] = lo[r] + hi[r] + bv;
    }
}

extern "C" void kernel_launch(void* const* d_in, const int* in_sizes, int n_in,
                              void* d_out, int out_size, void* d_ws, size_t ws_size,
                              hipStream_t stream) {
    const float* x      = (const float*)d_in[0];
    const int*   qw     = (const int*)d_in[1];
    const float* scales = (const float*)d_in[2];
    const float* bias   = (const float*)d_in[3];
    float*       out    = (float*)d_out;
    unsigned short* xT  = (unsigned short*)d_ws;   // 256 KB fragment-ordered x

    hipLaunchKernelGGL(xconv_kernel, dim3(64), dim3(256), 0, stream, x, xT);
    hipLaunchKernelGGL(qlin_kernel, dim3(OUT_F / 32), dim3(512), 0, stream,
                       xT, qw, scales, bias, out);
}

// Round 12
// 51.672 us; speedup vs baseline: 1.4544x; 1.0267x over previous
//
#include <hip/hip_runtime.h>

typedef __attribute__((ext_vector_type(8))) short short8;
typedef __attribute__((ext_vector_type(4))) float f32x4;
typedef __attribute__((ext_vector_type(4))) int   i32x4;

#define IN_F   4096
#define OUT_F  16384
#define NG     32
#define NCH    32           // 64-int chunks per wave K-half (2048/64)

// f32 -> bf16 round-to-nearest-even
static __device__ __forceinline__ short f2bf(float f) {
    union { float f; unsigned u; } c; c.f = f;
    unsigned u = c.u;
    u += 0x7FFF + ((u >> 16) & 1);
    return (short)(u >> 16);
}

// int8-range -> bf16 (exact for |v| <= 127)
static __device__ __forceinline__ short i2bf(int v) {
    union { float f; unsigned u; } c; c.f = (float)v;
    return (short)(c.u >> 16);
}

// Pre-pass: x[32][4096] f32 -> xT bf16 in MFMA-A-fragment order.
// xT layout: [t][h][ln][8] bf16, t = k/32, h = m-half, ln = l15*4 + l4.
__global__ __launch_bounds__(256)
void xconv_kernel(const float* __restrict__ x, unsigned short* __restrict__ xT) {
    const int g   = blockIdx.x * 256 + threadIdx.x;   // 16384 threads
    const int t   = g >> 7;
    const int rem = g & 127;
    const int h   = rem >> 6;
    const int ln  = rem & 63;
    const int l15 = ln >> 2;
    const int l4  = ln & 3;
    const float* src = x + (size_t)(16 * h + l15) * IN_F + t * 32 + l4 * 8;
    f32x4 a = *(const f32x4*)src;
    f32x4 b = *(const f32x4*)(src + 4);
    short8 o;
#pragma unroll
    for (int j = 0; j < 4; ++j) { o[j] = f2bf(a[j]); o[j + 4] = f2bf(b[j]); }
    *(short8*)(xT + (size_t)g * 8) = o;
}

// Main: ZERO mid-loop barriers. 512 thr = 8 fully-independent waves.
// Wave (grp, wk): 16 out-cols (grp) x K-half (wk); computes BOTH m-halves.
// Each wave stages its own 16 qw rows into its private LDS region
// (4 slots x 4 KB) and reads only its own data -> per-wave vmcnt(12)
// pipeline (depth 3), no s_barrier until the final reduce.
// Grid 256 = 1 block/CU, 8 free-running waves/CU, LDS 128 KB.
__global__ __launch_bounds__(512, 2)
void qlin_kernel(const unsigned short* __restrict__ xT,
                 const int*   __restrict__ qw,
                 const float* __restrict__ scales,
                 const float* __restrict__ bias,
                 float*       __restrict__ out)
{
    __shared__ int lqw[8][4][16][64];   // [wave][slot][row][int] = 128 KB

    const int tid  = threadIdx.x;
    const int wv   = tid >> 6;
    const int lane = tid & 63;
    const int l15  = lane & 15;
    const int l4   = lane >> 4;
    const int grp  = wv >> 1;          // col-group 0..3
    const int wk   = wv & 1;           // K-half
    const int col0 = blockIdx.x * 64 + grp * 16;
    const int swz  = (l15 & 7) << 4;

    // --- preloads (oldest VMEM; retired by the prologue wait) ---
    const float* scr = scales + (size_t)(col0 + l15) * NG + wk * 16;
    f32x4 sc4[4];
#pragma unroll
    for (int j = 0; j < 4; ++j) sc4[j] = *(const f32x4*)(scr + 4 * j);
    const float bv = bias[col0 + l15];
    asm volatile("" ::: "memory");     // pin: preloads before stage(0)

    // --- stage chunk c (64 ints) of this wave's 16 rows into slot sl ---
    // 4 instrs, each 1 KB = 4 rows x 256 B, LDS linear; global source
    // pre-swizzled by ((row&7)<<4) (read applies same XOR; rule #21).
    auto STAGE = [&](int c, int sl) {
#pragma unroll
        for (int i = 0; i < 4; ++i) {
            const int row = 4 * i + (lane >> 4);
            const int byt = ((lane & 15) * 16) ^ ((row & 7) << 4);
            const char* src = (const char*)(qw + (size_t)(col0 + row) * IN_F
                                            + wk * 2048 + c * 64) + byt;
            __builtin_amdgcn_global_load_lds(
                (const __attribute__((address_space(1))) unsigned int*)src,
                (__attribute__((address_space(3))) unsigned int*)&lqw[wv][sl][4 * i][0],
                16, 0, 0);
        }
    };

    // --- x fragments: 2 k-tiles x 2 m-halves per chunk, parity-2 park ---
    const unsigned short* xg = xT + (size_t)(l15 * 4 + l4) * 8;
    short8 xa[2][2][2];                // [parity][s][h]
    auto XLOAD = [&](int c, int par) {
        const int t0 = wk * 64 + c * 2;
#pragma unroll
        for (int s = 0; s < 2; ++s)
#pragma unroll
            for (int h = 0; h < 2; ++h)
                xa[par][s][h] = *(const short8*)(xg + (size_t)((t0 + s) * 2 + h) * 512);
    };

    f32x4 acc[2] = {{0.f, 0.f, 0.f, 0.f}, {0.f, 0.f, 0.f, 0.f}};

    // --- compute chunk c from slot sl (all indices static) ---
    auto COMPUTE = [&](int c, int sl, int par, float sc) {
        const char* lrow = (const char*)&lqw[wv][sl][l15][0];
        f32x4 ag[2] = {{0.f, 0.f, 0.f, 0.f}, {0.f, 0.f, 0.f, 0.f}};
#pragma unroll
        for (int s = 0; s < 2; ++s) {
            const int off = (s * 128 + l4 * 32) ^ swz;
            i32x4 q0 = *(const i32x4*)(lrow + off);
            i32x4 q1 = *(const i32x4*)(lrow + (off ^ 16));
            short8 bfr;
#pragma unroll
            for (int j = 0; j < 4; ++j) { bfr[j] = i2bf(q0[j]); bfr[j + 4] = i2bf(q1[j]); }
            ag[0] = __builtin_amdgcn_mfma_f32_16x16x32_bf16(xa[par][s][0], bfr, ag[0], 0, 0, 0);
            ag[1] = __builtin_amdgcn_mfma_f32_16x16x32_bf16(xa[par][s][1], bfr, ag[1], 0, 0, 0);
        }
#pragma unroll
        for (int h = 0; h < 2; ++h)
#pragma unroll
            for (int r = 0; r < 4; ++r) acc[h][r] += sc * ag[h][r];
    };

    // --- prologue: st0,x0,st1,x1,st2 (20 issued); vmcnt(12) retires st0+x0 ---
    STAGE(0, 0);
    asm volatile("" ::: "memory");
    XLOAD(0, 0);
    asm volatile("" ::: "memory");
    STAGE(1, 1);
    asm volatile("" ::: "memory");
    XLOAD(1, 1);
    asm volatile("" ::: "memory");
    STAGE(2, 2);
    asm volatile("s_waitcnt vmcnt(12)" ::: "memory");
    __builtin_amdgcn_sched_barrier(0);

    // --- steady (NO barriers): compute(i) || {x(i+2), stage(i+3)}; vmcnt(12)
    // At iter-i wait: outstanding st(i+1),x(i+1),st(i+2),x(i+2),st(i+3)=20;
    // retire 8 oldest = st(i+1)+x(i+1) -> next iter's inputs ready.
#pragma unroll
    for (int i = 0; i <= 28; ++i) {
        COMPUTE(i, i & 3, i & 1, sc4[i >> 3][(i >> 1) & 3]);
        XLOAD(i + 2, i & 1);
        asm volatile("" ::: "memory");
        STAGE(i + 3, (i + 3) & 3);
        asm volatile("s_waitcnt vmcnt(12)" ::: "memory");
        __builtin_amdgcn_sched_barrier(0);
    }
    // tail
    COMPUTE(29, 1, 1, sc4[3][2]);
    XLOAD(31, 1);
    asm volatile("s_waitcnt vmcnt(8)" ::: "memory");
    __builtin_amdgcn_sched_barrier(0);
    COMPUTE(30, 2, 0, sc4[3][3]);
    asm volatile("s_waitcnt vmcnt(0)" ::: "memory");
    __builtin_amdgcn_sched_barrier(0);
    COMPUTE(31, 3, 1, sc4[3][3]);

    // --- epilogue: single block-wide sync, pairwise wk-reduce, store ---
    __syncthreads();
    float* red = (float*)&lqw[0][0][0][0];    // [8][64][2][4] = 16 KB alias
#pragma unroll
    for (int h = 0; h < 2; ++h)
        *(f32x4*)&red[(size_t)(((wv * 64 + lane) * 2) + h) * 4] = acc[h];
    __syncthreads();
    if (wk == 0) {                             // even waves store
#pragma unroll
        for (int h = 0; h < 2; ++h) {
            f32x4 hi = *(const f32x4*)&red[(size_t)((((wv + 1) * 64 + lane) * 2) + h) * 4];
#pragma unroll
            for (int r = 0; r < 4; ++r)
                out[(size_t)(h * 16 + l4 * 4 + r) * OUT_F + col0 + l15] =
                    acc[h][r] + hi[r] + bv;
        }
    }
}

extern "C" void kernel_launch(void* const* d_in, const int* in_sizes, int n_in,
                              void* d_out, int out_size, void* d_ws, size_t ws_size,
                              hipStream_t stream) {
    const float* x      = (const float*)d_in[0];
    const int*   qw     = (const int*)d_in[1];
    const float* scales = (const float*)d_in[2];
    const float* bias   = (const float*)d_in[3];
    float*       out    = (float*)d_out;
    unsigned short* xT  = (unsigned short*)d_ws;   // 256 KB fragment-ordered x

    hipLaunchKernelGGL(xconv_kernel, dim3(64), dim3(256), 0, stream, x, xT);
    hipLaunchKernelGGL(qlin_kernel, dim3(OUT_F / 64), dim3(512), 0, stream,
                       xT, qw, scales, bias, out);
}